// Round 1
// baseline (134.818 us; speedup 1.0000x reference)
//
#include <hip/hip_runtime.h>
#include <hip/hip_bf16.h>

// Problem constants (from reference setup_inputs)
#define N_TF    1024
#define N_GENES 20000
#define WW      4
#define FANIN   16
#define BATCH   128

// ---------------------------------------------------------------------------
// Fast tanh: tanh(x) = 1 - 2/(exp(2x)+1). Robust at +/-inf (exp->inf => 1,
// exp->0 => -1). rcp via v_rcp_f32 (~1e-5 rel err, far below 6.9e-2 threshold).
__device__ __forceinline__ float fast_tanh(float x) {
    float t = __expf(2.0f * x);                  // v_exp_f32 path
    return 1.0f - 2.0f * __builtin_amdgcn_rcpf(t + 1.0f);
}

// ---------------------------------------------------------------------------
// features [B=128][N_TF=1024] row-major  ->  xT [N_TF][B] row-major
// Classic 32x32 LDS tile transpose; both global read & write coalesced.
__global__ __launch_bounds__(256) void transpose_kernel(
    const float* __restrict__ in, float* __restrict__ out)
{
    __shared__ float tile[32][33];               // +1 pad: no bank conflicts
    const int bx = blockIdx.x;                   // N_TF tile: 0..31
    const int by = blockIdx.y;                   // B tile:    0..3
    const int tx = threadIdx.x;                  // 0..31
    const int ty = threadIdx.y;                  // 0..7
#pragma unroll
    for (int k = 0; k < 32; k += 8)
        tile[ty + k][tx] = in[(by * 32 + ty + k) * N_TF + bx * 32 + tx];
    __syncthreads();
#pragma unroll
    for (int k = 0; k < 32; k += 8)
        out[(bx * 32 + ty + k) * BATCH + by * 32 + tx] = tile[tx][ty + k];
}

// ---------------------------------------------------------------------------
// Fused 3-layer kernel. One wave per gene (4 genes/wave sequentially),
// 4 waves/block => 16 genes/block, grid = 20000/16 = 1250 blocks.
// Lane l handles batch elements (2l, 2l+1) via float2 loads from xT.
constexpr int GENES_PER_BLOCK = 16;
constexpr int GENES_PER_WAVE  = 4;
constexpr int YPAD            = 130;  // LDS row stride (floats): conflict-free

__global__ __launch_bounds__(256) void fused_kernel(
    const float* __restrict__ xT,     // [N_TF][B]
    const float* __restrict__ w1,     // [M*FANIN]
    const float* __restrict__ b1,     // [M]
    const int*   __restrict__ in1,    // [M*FANIN]
    const float* __restrict__ w2,     // [M*W]
    const float* __restrict__ b2,     // [M]
    const float* __restrict__ w3,     // [N_GENES*W]
    const float* __restrict__ b3,     // [N_GENES]
    float*       __restrict__ out)    // [B][N_GENES]
{
    __shared__ float ytile[GENES_PER_BLOCK * YPAD];

    const int tid  = threadIdx.x;
    const int wid  = __builtin_amdgcn_readfirstlane(tid >> 6);  // uniform wave id
    const int lane = tid & 63;
    const int g_base = blockIdx.x * GENES_PER_BLOCK + wid * GENES_PER_WAVE;
    const float2* __restrict__ xT2 = (const float2*)xT;

    for (int gi = 0; gi < GENES_PER_WAVE; ++gi) {
        const int g = g_base + gi;

        // ---- Layer 1: 4 nodes x 16 random-TF edges -------------------------
        float2 h1[WW];
#pragma unroll
        for (int i = 0; i < WW; ++i) {
            const int o = g * WW + i;
            const int ebase = o * FANIN;
            float ax = 0.0f, ay = 0.0f;
#pragma unroll
            for (int j = 0; j < FANIN; ++j) {
                const float w   = w1[ebase + j];     // wave-uniform -> s_load
                const int   idx = in1[ebase + j];    // wave-uniform -> s_load
                const float2 xv = xT2[idx * (BATCH / 2) + lane];  // coalesced 512B column
                ax += w * xv.x;
                ay += w * xv.y;
            }
            const float bb = b1[o];
            h1[i].x = fast_tanh(ax + bb);
            h1[i].y = fast_tanh(ay + bb);
        }

        // ---- Layer 2: dense 4x4 within the gene ----------------------------
        float2 h2[WW];
#pragma unroll
        for (int i = 0; i < WW; ++i) {
            const int o = g * WW + i;
            float sx = b2[o], sy = sx;
#pragma unroll
            for (int k = 0; k < WW; ++k) {
                const float w = w2[o * WW + k];
                sx += w * h1[k].x;
                sy += w * h1[k].y;
            }
            h2[i].x = fast_tanh(sx);
            h2[i].y = fast_tanh(sy);
        }

        // ---- Layer 3: sum the 4 nodes --------------------------------------
        float yx = b3[g], yy = yx;
#pragma unroll
        for (int i = 0; i < WW; ++i) {
            const float w = w3[g * WW + i];
            yx += w * h2[i].x;
            yy += w * h2[i].y;
        }

        // ---- stash into LDS tile (transposed store later) ------------------
        const int gl = wid * GENES_PER_WAVE + gi;
        ytile[gl * YPAD + 2 * lane]     = yx;
        ytile[gl * YPAD + 2 * lane + 1] = yy;
    }

    __syncthreads();

    // ---- coalesced store: runs of 16 consecutive genes per batch row -------
    const int g0 = blockIdx.x * GENES_PER_BLOCK;
#pragma unroll
    for (int it = 0; it < (GENES_PER_BLOCK * BATCH) / 256; ++it) {
        const int idx = it * 256 + tid;
        const int gl  = idx & (GENES_PER_BLOCK - 1);
        const int b   = idx >> 4;                    // GENES_PER_BLOCK == 16
        out[b * N_GENES + g0 + gl] = ytile[gl * YPAD + b];
    }
}

// ---------------------------------------------------------------------------
extern "C" void kernel_launch(void* const* d_in, const int* in_sizes, int n_in,
                              void* d_out, int out_size, void* d_ws, size_t ws_size,
                              hipStream_t stream)
{
    // setup_inputs order: features, w1, b1, w2, b2, w3, b3, out1, in1, out2, in2, out3, in3
    const float* features = (const float*)d_in[0];
    const float* w1 = (const float*)d_in[1];
    const float* b1 = (const float*)d_in[2];
    const float* w2 = (const float*)d_in[3];
    const float* b2 = (const float*)d_in[4];
    const float* w3 = (const float*)d_in[5];
    const float* b3 = (const float*)d_in[6];
    const int*   in1 = (const int*)d_in[8];
    float* out = (float*)d_out;

    float* xT = (float*)d_ws;                    // 1024*128*4 = 512 KiB scratch

    hipLaunchKernelGGL(transpose_kernel, dim3(32, 4), dim3(32, 8), 0, stream,
                       features, xT);
    hipLaunchKernelGGL(fused_kernel, dim3(N_GENES / GENES_PER_BLOCK), dim3(256), 0, stream,
                       xT, w1, b1, in1, w2, b2, w3, b3, out);
}

// Round 2
// 117.330 us; speedup vs baseline: 1.1491x; 1.1491x over previous
//
#include <hip/hip_runtime.h>
#include <hip/hip_fp16.h>

// Problem constants (from reference setup_inputs)
#define N_TF    1024
#define N_GENES 20000
#define WW      4
#define FANIN   16
#define BATCH   128
#define MM      (N_GENES * WW)          // 80000
#define NNZ1    (MM * FANIN)            // 1,280,000

typedef unsigned int uint32;

// ---------------------------------------------------------------------------
// Fast tanh: tanh(x) = 1 - 2/(exp(2x)+1). Robust at +/-inf.
__device__ __forceinline__ float fast_tanh(float x) {
    float t = __expf(2.0f * x);
    return 1.0f - 2.0f * __builtin_amdgcn_rcpf(t + 1.0f);
}

// ---------------------------------------------------------------------------
// features [B=128][N_TF=1024] fp32  ->  xh [N_TF][B=128] fp16
__global__ __launch_bounds__(256) void transpose_cvt_kernel(
    const float* __restrict__ in, __half* __restrict__ out)
{
    __shared__ float tile[32][33];
    const int bx = blockIdx.x;            // N_TF tile 0..31
    const int by = blockIdx.y;            // B tile 0..3
    const int tx = threadIdx.x;           // 0..31
    const int ty = threadIdx.y;           // 0..7
#pragma unroll
    for (int k = 0; k < 32; k += 8)
        tile[ty + k][tx] = in[(by * 32 + ty + k) * N_TF + bx * 32 + tx];
    __syncthreads();
#pragma unroll
    for (int k = 0; k < 32; k += 8)
        out[(bx * 32 + ty + k) * BATCH + by * 32 + tx] =
            __float2half(tile[tx][ty + k]);
}

// ---------------------------------------------------------------------------
// w1 fp32 -> duplicated-fp16 pack: w1d[i] = (h<<16)|h  (one v_pk_fma src)
__global__ __launch_bounds__(256) void pack_w1_kernel(
    const float* __restrict__ w1, uint32* __restrict__ w1d)
{
    const int i = blockIdx.x * 256 + threadIdx.x;
    if (i < NNZ1) {
        __half h = __float2half(w1[i]);
        uint32 u = (uint32)__half_as_ushort(h);
        w1d[i] = (u << 16) | u;
    }
}

// ---------------------------------------------------------------------------
// Fused 3-layer kernel. GENES_PER_WAVE=2, 4 waves/block => 8 genes/block,
// grid = 20000/8 = 2500 blocks (~10 blocks/CU available -> full occupancy).
// Lane l handles batch pair (2l, 2l+1): one dword fp16x2 gather per edge,
// one v_pk_fma_f16 accumulate per edge.
constexpr int GENES_PER_BLOCK = 8;
constexpr int GENES_PER_WAVE  = 2;
constexpr int YPAD            = 130;   // LDS row stride (floats)

template <bool PACKW>
__global__ __launch_bounds__(256) void fused_kernel(
    const __half* __restrict__ xh,     // [N_TF][B] fp16
    const uint32* __restrict__ w1d,    // [NNZ1] duplicated fp16 (if PACKW)
    const float*  __restrict__ w1,     // [NNZ1] fp32 (fallback)
    const float*  __restrict__ b1,     // [M]
    const int*    __restrict__ in1,    // [NNZ1]
    const float*  __restrict__ w2,     // [M*W]
    const float*  __restrict__ b2,     // [M]
    const float*  __restrict__ w3,     // [N_GENES*W]
    const float*  __restrict__ b3,     // [N_GENES]
    float*        __restrict__ out)    // [B][N_GENES]
{
    __shared__ float ytile[GENES_PER_BLOCK * YPAD];

    const int tid  = threadIdx.x;
    const int wid  = __builtin_amdgcn_readfirstlane(tid >> 6);   // uniform
    const int lane = tid & 63;
    const int g_base = blockIdx.x * GENES_PER_BLOCK + wid * GENES_PER_WAVE;
    const __half2* __restrict__ xc = (const __half2*)xh;

#pragma unroll
    for (int gi = 0; gi < GENES_PER_WAVE; ++gi) {
        const int g = g_base + gi;

        // ---- Layer 1: 4 nodes x 16 random-TF edges, fp16x2 pk-fma ---------
        float2 h1[WW];
#pragma unroll
        for (int i = 0; i < WW; ++i) {
            const int o = g * WW + i;
            const int ebase = o * FANIN;
            __half2 acc = __half2half2(__ushort_as_half((unsigned short)0));
#pragma unroll
            for (int j = 0; j < FANIN; ++j) {
                const int idx = in1[ebase + j];               // uniform s_load
                const __half2 xv = xc[idx * (BATCH / 2) + lane]; // 256B wave load
                __half2 wv;
                if (PACKW) {
                    const uint32 wd = w1d[ebase + j];         // uniform s_load
                    wv = *reinterpret_cast<const __half2*>(&wd);
                } else {
                    wv = __half2half2(__float2half(w1[ebase + j]));
                }
                acc = __hfma2(wv, xv, acc);
            }
            const float2 af = __half22float2(acc);
            const float  bb = b1[o];
            h1[i].x = fast_tanh(af.x + bb);
            h1[i].y = fast_tanh(af.y + bb);
        }

        // ---- Layer 2: dense 4x4 within the gene (fp32) ---------------------
        float2 h2[WW];
#pragma unroll
        for (int i = 0; i < WW; ++i) {
            const int o = g * WW + i;
            float sx = b2[o], sy = sx;
#pragma unroll
            for (int k = 0; k < WW; ++k) {
                const float w = w2[o * WW + k];
                sx += w * h1[k].x;
                sy += w * h1[k].y;
            }
            h2[i].x = fast_tanh(sx);
            h2[i].y = fast_tanh(sy);
        }

        // ---- Layer 3: sum the 4 nodes --------------------------------------
        float yx = b3[g], yy = yx;
#pragma unroll
        for (int i = 0; i < WW; ++i) {
            const float w = w3[g * WW + i];
            yx += w * h2[i].x;
            yy += w * h2[i].y;
        }

        const int gl = wid * GENES_PER_WAVE + gi;
        ytile[gl * YPAD + 2 * lane]     = yx;
        ytile[gl * YPAD + 2 * lane + 1] = yy;
    }

    __syncthreads();

    // ---- coalesced-ish store: runs of 8 consecutive genes per batch row ----
    const int g0 = blockIdx.x * GENES_PER_BLOCK;
#pragma unroll
    for (int it = 0; it < (GENES_PER_BLOCK * BATCH) / 256; ++it) {
        const int idx = it * 256 + tid;
        const int gl  = idx & (GENES_PER_BLOCK - 1);
        const int b   = idx >> 3;                 // GENES_PER_BLOCK == 8
        out[b * N_GENES + g0 + gl] = ytile[gl * YPAD + b];
    }
}

// ---------------------------------------------------------------------------
extern "C" void kernel_launch(void* const* d_in, const int* in_sizes, int n_in,
                              void* d_out, int out_size, void* d_ws, size_t ws_size,
                              hipStream_t stream)
{
    // order: features, w1, b1, w2, b2, w3, b3, out1, in1, out2, in2, out3, in3
    const float* features = (const float*)d_in[0];
    const float* w1 = (const float*)d_in[1];
    const float* b1 = (const float*)d_in[2];
    const float* w2 = (const float*)d_in[3];
    const float* b2 = (const float*)d_in[4];
    const float* w3 = (const float*)d_in[5];
    const float* b3 = (const float*)d_in[6];
    const int*   in1 = (const int*)d_in[8];
    float* out = (float*)d_out;

    // ws layout: [w1d: NNZ1 uint32 = 5.0 MiB][xh: N_TF*B fp16 = 256 KiB]
    const size_t w1d_bytes = (size_t)NNZ1 * sizeof(uint32);
    const size_t xh_bytes  = (size_t)N_TF * BATCH * sizeof(__half);
    uint32* w1d = (uint32*)d_ws;
    const bool packw = ws_size >= w1d_bytes + xh_bytes;
    __half* xh = packw ? (__half*)((char*)d_ws + w1d_bytes) : (__half*)d_ws;

    hipLaunchKernelGGL(transpose_cvt_kernel, dim3(32, 4), dim3(32, 8), 0, stream,
                       features, xh);
    if (packw) {
        hipLaunchKernelGGL(pack_w1_kernel, dim3((NNZ1 + 255) / 256), dim3(256), 0,
                           stream, w1, w1d);
        hipLaunchKernelGGL((fused_kernel<true>), dim3(N_GENES / GENES_PER_BLOCK),
                           dim3(256), 0, stream,
                           xh, w1d, w1, b1, in1, w2, b2, w3, b3, out);
    } else {
        hipLaunchKernelGGL((fused_kernel<false>), dim3(N_GENES / GENES_PER_BLOCK),
                           dim3(256), 0, stream,
                           xh, (const uint32*)nullptr, w1, b1, in1, w2, b2, w3, b3, out);
    }
}